// Round 6
// baseline (1477.952 us; speedup 1.0000x reference)
//
#include <hip/hip_runtime.h>
#include <cstdint>

#define NPART 32768
#define HALFN 16384

// ws float-offsets
#define WS_W     0        // [32][64]
#define WS_M     2048     // [32][64]
#define WS_B     4096     // [65][32]
#define WS_C0    6176
#define WS_KI    6178     // 2 uints
#define WS_NK    6180     // 128 uints
#define WS_UK    6308     // 130 uints -> 6438
#define WS_P4    6440     // u64[256][4]: (PMY,PMLW,PZY,PZLW) seq-stamped -> 8488
#define WS_PSE   8488     // float[256][64] -> 24872
#define WS_QP64  24872    // u64[256] seq-stamped -> 25384
#define WS_RBUF  25384    // float[64] r-vector (combiner -> all)
#define WS_RST   25448    // u32[256*4] per-block r stamps (16B stride) -> 26472
#define WS_END   26472

#define ATS32(p, v) __hip_atomic_store((p), (v), __ATOMIC_RELAXED, __HIP_MEMORY_SCOPE_AGENT)
#define ATL32(p)    __hip_atomic_load((p), __ATOMIC_RELAXED, __HIP_MEMORY_SCOPE_AGENT)
#define ATS64(p, v) __hip_atomic_store((p), (v), __ATOMIC_RELAXED, __HIP_MEMORY_SCOPE_AGENT)
#define ATL64(p)    __hip_atomic_load((p), __ATOMIC_RELAXED, __HIP_MEMORY_SCOPE_AGENT)

struct HK { uint32_t a, b; };

// JAX threefry2x32 (20 rounds, 5 key injections)
__host__ __device__ inline HK tf2x32(uint32_t k0, uint32_t k1, uint32_t x0, uint32_t x1) {
  uint32_t kx = k0 ^ k1 ^ 0x1BD11BDAu;
#define TF_R(r) { x0 += x1; x1 = (x1 << (r)) | (x1 >> (32 - (r))); x1 ^= x0; }
  x0 += k0; x1 += k1;
  TF_R(13) TF_R(15) TF_R(26) TF_R(6)
  x0 += k1; x1 += kx + 1u;
  TF_R(17) TF_R(29) TF_R(16) TF_R(24)
  x0 += kx; x1 += k0 + 2u;
  TF_R(13) TF_R(15) TF_R(26) TF_R(6)
  x0 += k0; x1 += k1 + 3u;
  TF_R(17) TF_R(29) TF_R(16) TF_R(24)
  x0 += k1; x1 += kx + 4u;
  TF_R(13) TF_R(15) TF_R(26) TF_R(6)
  x0 += kx; x1 += k0 + 5u;
#undef TF_R
  HK r; r.a = x0; r.b = x1; return r;
}

// XLA ErfInv32 polynomial
__device__ inline float erfinv_f(float x) {
  float w = -log1pf(-x * x);
  float p;
  if (w < 5.0f) {
    w -= 2.5f;
    p = 2.81022636e-08f;
    p = fmaf(p, w, 3.43273939e-07f);
    p = fmaf(p, w, -3.5233877e-06f);
    p = fmaf(p, w, -4.39150654e-06f);
    p = fmaf(p, w, 0.00021858087f);
    p = fmaf(p, w, -0.00125372503f);
    p = fmaf(p, w, -0.00417768164f);
    p = fmaf(p, w, 0.246640727f);
    p = fmaf(p, w, 1.50140941f);
  } else {
    w = sqrtf(w) - 3.0f;
    p = -0.000200214257f;
    p = fmaf(p, w, 0.000100950558f);
    p = fmaf(p, w, 0.00134934322f);
    p = fmaf(p, w, -0.00367342844f);
    p = fmaf(p, w, 0.00573950773f);
    p = fmaf(p, w, -0.0076224613f);
    p = fmaf(p, w, 0.00943887047f);
    p = fmaf(p, w, 1.00167406f);
    p = fmaf(p, w, 2.83297682f);
  }
  return p * x;
}

__device__ inline float u01(uint32_t bits) {
  return __uint_as_float((bits >> 9) | 0x3f800000u) - 1.0f;
}

__device__ inline uint64_t packfs(float v, uint32_t sq) {
  return ((uint64_t)sq << 32) | (uint64_t)__float_as_uint(v);
}

// Precompute: chol(R), Linv, W = Linv C, M = W Qc, b[t] = Linv obs_t, C0, keys;
// zero all stamped exchange regions.
__global__ __launch_bounds__(1024) void kp_kernel(float* __restrict__ ws,
    const float* __restrict__ obs, const float* __restrict__ Cm,
    const float* __restrict__ Qc, const float* __restrict__ Rc) {
  __shared__ float Ls[32][32];
  __shared__ float Li[32][32];
  __shared__ float Wsh[32][64];
  const int tid = threadIdx.x;
  const int i = tid >> 5, j = tid & 31;
  uint32_t* wsu = (uint32_t*)ws;
  // zero exchange regions (stamps -> 0)
  for (int idx = WS_P4 + tid; idx < WS_END; idx += 1024) wsu[idx] = 0u;
  // keys (parallel over t)
  if (tid <= 64) {
    HK p0 = tf2x32(0u, 42u, 0u, 2u);
    HK p1 = tf2x32(0u, 42u, 1u, 3u);
    uint32_t ks0 = p0.b, ks1 = p1.b;
    HK f = tf2x32(ks0, ks1, 0u, (uint32_t)tid);
    HK q0 = tf2x32(f.a, f.b, 0u, 2u);
    HK q1 = tf2x32(f.a, f.b, 1u, 3u);
    wsu[WS_UK + 2 * tid] = q0.a; wsu[WS_UK + 2 * tid + 1] = q1.a;
    if (tid < 64) { wsu[WS_NK + 2 * tid] = q0.b; wsu[WS_NK + 2 * tid + 1] = q1.b; }
    if (tid == 0) { wsu[WS_KI] = p0.a; wsu[WS_KI + 1] = p1.a; }
  }
  // R = Rc Rc^T
  {
    float a = 0.0f;
    for (int k = 0; k < 32; ++k) a = fmaf(Rc[i * 32 + k], Rc[j * 32 + k], a);
    Ls[i][j] = a;
  }
  __syncthreads();
  for (int k = 0; k < 32; ++k) {
    if (tid == 0) Ls[k][k] = sqrtf(Ls[k][k]);
    __syncthreads();
    if (tid > k && tid < 32) Ls[tid][k] /= Ls[k][k];
    __syncthreads();
    if (i > k && j > k && j <= i) Ls[i][j] = fmaf(-Ls[i][k], Ls[j][k], Ls[i][j]);
    __syncthreads();
  }
  if (tid < 32) {
    for (int r = 0; r < 32; ++r) Li[r][tid] = 0.0f;
    Li[tid][tid] = 1.0f / Ls[tid][tid];
    for (int r = tid + 1; r < 32; ++r) {
      float s = 0.0f;
      for (int m = tid; m < r; ++m) s = fmaf(Ls[r][m], Li[m][tid], s);
      Li[r][tid] = -s / Ls[r][r];
    }
  }
  __syncthreads();
  if (tid == 0) {
    float ld = 0.0f;
    for (int k = 0; k < 32; ++k) ld += logf(Ls[k][k]);
    ws[WS_C0] = -0.5f * 32.0f * 1.8378770664093453f - ld;
  }
  for (int idx = tid; idx < 2048; idx += 1024) {
    int o = idx >> 6, d = idx & 63;
    float a = 0.0f;
    for (int k = 0; k < 32; ++k) a = fmaf(Li[o][k], Cm[k * 64 + d], a);
    Wsh[o][d] = a;
    ws[WS_W + idx] = a;
  }
  __syncthreads();
  for (int idx = tid; idx < 2048; idx += 1024) {
    int o = idx >> 6, d = idx & 63;
    float a = 0.0f;
    for (int k = 0; k < 64; ++k) a = fmaf(Wsh[o][k], Qc[k * 64 + d], a);
    ws[WS_M + idx] = a;
  }
  for (int idx = tid; idx < 2080; idx += 1024) {
    int t = idx >> 5, o = idx & 31;
    float a = 0.0f;
    for (int k = 0; k < 32; ++k) a = fmaf(Li[o][k], obs[t * 32 + k], a);
    ws[WS_B + idx] = a;
  }
}

// Persistent cooperative kernel: 256 blocks x 512 threads.
// Block 0 = combiner (also owns particles): sole reader of P4/PSE partials,
// publishes r[64] + per-block private stamps. Consumers: 1-lane stamp poll,
// read r, quad partial, redundant meanH, tail. All LLC traffic via relaxed
// agent atomics (no fences).
__global__ __launch_bounds__(512, 2) void kmain_kernel(
    float* __restrict__ ws, const float* __restrict__ Am,
    const float* __restrict__ Qcg, const float* __restrict__ Qt,
    float* __restrict__ dout) {
  __shared__ __align__(16) float Ms[2048];
  __shared__ __align__(16) float Wm[2048];
  __shared__ __align__(16) float As[4096];
  __shared__ __align__(16) float Qcs[4096];
  __shared__ __align__(16) float Qs[1024];
  __shared__ float hC[32];
  __shared__ float rS[64], uS[64], mnS[64];
  __shared__ float ebL[256];
  __shared__ float redA[256], redB[256];
  __shared__ float SEw[8][64];
  __shared__ float wred[8][4];
  __shared__ float sc[8];
  __shared__ uint32_t keyL[260];  // [0..127] nk, [128..257] uk, [258..259] ki

  const int tid = threadIdx.x;
  const int bid = blockIdx.x;
  uint32_t* wsu = (uint32_t*)ws;
  uint64_t* p4 = (uint64_t*)(ws + WS_P4);
  uint64_t* qp64 = (uint64_t*)(ws + WS_QP64);
  uint32_t* rst = wsu + WS_RST;

  // prologue loads (read-only data; plain cached loads)
  for (int i = tid; i < 2048; i += 512) { Ms[i] = ws[WS_M + i]; Wm[i] = ws[WS_W + i]; }
  for (int i = tid; i < 4096; i += 512) As[i] = Am[i];
  if (bid == 0) for (int i = tid; i < 4096; i += 512) Qcs[i] = Qcg[i];
  {
    const int i0 = (bid >> 2) * 4096 + (bid & 3) * 1024;
    for (int i = tid; i < 1024; i += 512) Qs[i] = Qt[i0 + i];
  }
  for (int i = tid; i < 128; i += 512) keyL[i] = wsu[WS_NK + i];
  for (int i = tid; i < 130; i += 512) keyL[128 + i] = wsu[WS_UK + i];
  if (tid == 0) { keyL[258] = wsu[WS_KI]; keyL[259] = wsu[WS_KI + 1]; sc[4] = 0.0f; }
  if (tid < 32) hC[tid] = ws[WS_B + tid];
  const float C0 = ws[WS_C0];
  __syncthreads();

  const int pr = tid >> 3;          // pair within block
  const int l8 = tid & 7;
  const int p = bid * 64 + pr;      // global pair (= lo particle)
  const int d0 = l8 * 8;
  const int wv = tid >> 6, ln = tid & 63;

  float Elo[8], Ehi[8], gl, gh;
  float aL[4], aH[4];               // precomputed Mat*E quarter (dims ob..ob+3)

  auto poll64 = [&](uint64_t* pp, uint32_t sq) -> float {
    uint64_t q;
    for (;;) {
      q = ATL64(pp);
      if ((uint32_t)(q >> 32) >= sq) break;
      __builtin_amdgcn_s_sleep(1);
    }
    return __uint_as_float((uint32_t)q);
  };
  // slower-cadence variant for the mass QP poll (contention control)
  auto poll64b = [&](uint64_t* pp, uint32_t sq) -> float {
    uint64_t q;
    for (;;) {
      q = ATL64(pp);
      if ((uint32_t)(q >> 32) >= sq) break;
      __builtin_amdgcn_s_sleep(4);
    }
    return __uint_as_float((uint32_t)q);
  };

  auto genE8 = [&](uint32_t k0, uint32_t k1) {
    const uint32_t fb = (uint32_t)(p * 64 + d0);
#pragma unroll
    for (int j = 0; j < 8; ++j) {
      HK o = tf2x32(k0, k1, fb + (uint32_t)j, fb + (uint32_t)j + 1048576u);
      float fl = u01(o.a), fh = u01(o.b);
      float ul = fmaxf(-0.99999994f, fmaf(fl, 2.0f, -0.99999994f));
      float uh = fmaxf(-0.99999994f, fmaf(fh, 2.0f, -0.99999994f));
      Elo[j] = 1.41421354f * erfinv_f(ul);
      Ehi[j] = 1.41421354f * erfinv_f(uh);
    }
  };
  auto genG = [&](uint32_t k0, uint32_t k1) {
    HK og = tf2x32(k0, k1, (uint32_t)p, (uint32_t)(p + 16384));
    gl = -logf(-logf(u01(og.a) + 1e-10f) + 1e-10f);
    gh = -logf(-logf(u01(og.b) + 1e-10f) + 1e-10f);
  };

  // ring reduce-scatter Mat*E over the 8 lanes of a pair -> aL/aH for dims
  // ob = ((l8+7)&7)*4 .. +3.  Independent of h -> shadow work.
  auto ringME = [&](const float* matL) {
#pragma unroll
    for (int q = 0; q < 4; ++q) { aL[q] = 0.f; aH[q] = 0.f; }
#pragma unroll
    for (int k = 0; k < 8; ++k) {
      if (k) {
#pragma unroll
        for (int q = 0; q < 4; ++q) {
          aL[q] = __shfl(aL[q], (l8 + 1) & 7, 8);
          aH[q] = __shfl(aH[q], (l8 + 1) & 7, 8);
        }
      }
      const int ow = ((l8 + k) & 7) * 4;
#pragma unroll
      for (int q = 0; q < 4; ++q) {
        const float* mr = matL + (ow + q) * 64 + d0;
        float4 m0 = *(const float4*)mr;
        float4 m1 = *(const float4*)(mr + 4);
        float t0 = aL[q];
        t0 = fmaf(m0.x, Elo[0], t0); t0 = fmaf(m0.y, Elo[1], t0);
        t0 = fmaf(m0.z, Elo[2], t0); t0 = fmaf(m0.w, Elo[3], t0);
        t0 = fmaf(m1.x, Elo[4], t0); t0 = fmaf(m1.y, Elo[5], t0);
        t0 = fmaf(m1.z, Elo[6], t0); t0 = fmaf(m1.w, Elo[7], t0);
        aL[q] = t0;
        float t1 = aH[q];
        t1 = fmaf(m0.x, Ehi[0], t1); t1 = fmaf(m0.y, Ehi[1], t1);
        t1 = fmaf(m0.z, Ehi[2], t1); t1 = fmaf(m0.w, Ehi[3], t1);
        t1 = fmaf(m1.x, Ehi[4], t1); t1 = fmaf(m1.y, Ehi[5], t1);
        t1 = fmaf(m1.z, Ehi[6], t1); t1 = fmaf(m1.w, Ehi[7], t1);
        aH[q] = t1;
      }
    }
  };

  // z = hC - precomputed Mat*E; lw, y, block softmax partials + weighted-E
  // sums; publish PSE then vmcnt-drain then stamped P4 header.
  auto tailStore = [&](uint32_t sq) {
    const int ob = ((l8 + 7) & 7) * 4;
    float s2l = 0.f, s2h = 0.f;
#pragma unroll
    for (int q = 0; q < 4; ++q) {
      float zl = hC[ob + q] - aL[q], zh = hC[ob + q] - aH[q];
      s2l = fmaf(zl, zl, s2l); s2h = fmaf(zh, zh, s2h);
    }
#pragma unroll
    for (int m = 1; m < 8; m <<= 1) { s2l += __shfl_xor(s2l, m, 8); s2h += __shfl_xor(s2h, m, 8); }
    const float lwL = C0 - 0.5f * s2l, lwH = C0 - 0.5f * s2h;
    const float yl = (lwL + gl) * 2.0f, yh = (lwH + gh) * 2.0f;
    float mv = fmaxf(yl, yh), ml = fmaxf(lwL, lwH);
#pragma unroll
    for (int m = 1; m < 64; m <<= 1) {
      mv = fmaxf(mv, __shfl_xor(mv, m, 64));
      ml = fmaxf(ml, __shfl_xor(ml, m, 64));
    }
    if (ln == 0) { wred[wv][0] = mv; wred[wv][1] = ml; }
    __syncthreads();
    if (tid == 0) {
      float a = wred[0][0], b = wred[0][1];
      for (int q = 1; q < 8; ++q) { a = fmaxf(a, wred[q][0]); b = fmaxf(b, wred[q][1]); }
      sc[0] = a; sc[1] = b;
    }
    __syncthreads();
    const float myb = sc[0], mlb = sc[1];
    const float wLo = expf(yl - myb), wHi = expf(yh - myb);
    float vzy = (l8 == 0) ? (wLo + wHi) : 0.0f;
    float vzl = (l8 == 0) ? (expf(lwL - mlb) + expf(lwH - mlb)) : 0.0f;
#pragma unroll
    for (int m = 1; m < 64; m <<= 1) { vzy += __shfl_xor(vzy, m, 64); vzl += __shfl_xor(vzl, m, 64); }
    if (ln == 0) { wred[wv][2] = vzy; wred[wv][3] = vzl; }
    float v[8];
#pragma unroll
    for (int j = 0; j < 8; ++j) v[j] = fmaf(wHi, Ehi[j], wLo * Elo[j]);
#pragma unroll
    for (int m = 8; m < 64; m <<= 1) {
#pragma unroll
      for (int j = 0; j < 8; ++j) v[j] += __shfl_xor(v[j], m, 64);
    }
    if (ln < 8) {
#pragma unroll
      for (int j = 0; j < 8; ++j) SEw[wv][ln * 8 + j] = v[j];
    }
    __syncthreads();
    if (tid < 64) {
      float ssum = SEw[0][tid];
      for (int q = 1; q < 8; ++q) ssum += SEw[q][tid];
      ATS32(ws + WS_PSE + (bid << 6) + tid, ssum);
    }
    // wave 0: drain PSE stores to LLC, then publish stamped header
    if (tid < 64) asm volatile("s_waitcnt vmcnt(0)" ::: "memory");
    if (tid == 0) {
      float zy = wred[0][2], zl2 = wred[0][3];
      for (int q = 1; q < 8; ++q) { zy += wred[q][2]; zl2 += wred[q][3]; }
      uint64_t* bp = p4 + bid * 4;
      ATS64(bp + 0, packfs(myb, sq));
      ATS64(bp + 1, packfs(mlb, sq));
      ATS64(bp + 2, packfs(zy, sq));
      ATS64(bp + 3, packfs(zl2, sq));
    }
  };

  // COMBINER (bid 0): poll all P4, reduce (bit-identical to R5 combine),
  // compute u then r; publish r + per-block stamps.
  auto combA = [&](int s) {
    const uint32_t sq = (uint32_t)(s + 1);
    float pmv = 0.f, pml = 0.f, pzyv = 0.f, pzlv = 0.f;
    if (tid < 256) {
      uint64_t* bp = p4 + tid * 4;
      pmv = poll64(bp + 0, sq);
      pml = poll64(bp + 1, sq);
      pzyv = poll64(bp + 2, sq);
      pzlv = poll64(bp + 3, sq);
      redA[tid] = pmv; redB[tid] = pml;
    }
    __syncthreads();
    asm volatile("" ::: "memory");
    float pse[32];
    {
      const int d = tid & 63, c = tid >> 6;
#pragma unroll
      for (int b8 = 0; b8 < 32; ++b8)
        pse[b8] = ATL32(ws + WS_PSE + (((c << 5) + b8) << 6) + d);
    }
    for (int st = 128; st > 0; st >>= 1) {
      if (tid < st) {
        redA[tid] = fmaxf(redA[tid], redA[tid + st]);
        redB[tid] = fmaxf(redB[tid], redB[tid + st]);
      }
      __syncthreads();
    }
    const float myg = redA[0], mlwg = redB[0];
    __syncthreads();
    if (tid < 256) {
      float e = expf(pmv - myg);
      ebL[tid] = e;
      redA[tid] = e * pzyv;
      redB[tid] = expf(pml - mlwg) * pzlv;
    }
    __syncthreads();
    for (int st = 128; st > 0; st >>= 1) {
      if (tid < st) { redA[tid] += redA[tid + st]; redB[tid] += redB[tid + st]; }
      __syncthreads();
    }
    if (tid == 0) {
      sc[2] = redA[0];
      if (s > 0) sc[4] += mlwg + logf(redB[0]);
    }
    __syncthreads();
    const float Zy = sc[2];
    {
      const int d = tid & 63, c = tid >> 6;
      float pp = 0.0f;
#pragma unroll
      for (int b8 = 0; b8 < 32; ++b8)
        pp = fmaf(ebL[(c << 5) + b8], pse[b8], pp);
      SEw[c][d] = pp;
    }
    __syncthreads();
    if (tid < 64) {
      float sg = SEw[0][tid];
      for (int c = 1; c < 8; ++c) sg += SEw[c][tid];
      uS[tid] = sg / Zy;
    }
    __syncthreads();
    if (tid < 64) {
      float r;
      if (s == 0) r = uS[tid];
      else {
        r = mnS[tid];
        const float* qr = Qcs + tid * 64;
        for (int k2 = 0; k2 < 64; ++k2) r = fmaf(uS[k2], qr[k2], r);
      }
      rS[tid] = r;
      ATS32(ws + WS_RBUF + tid, r);
    }
    if (tid < 64) asm volatile("s_waitcnt vmcnt(0)" ::: "memory");
    __syncthreads();
    if (tid < 256) ATS32(rst + tid * 4, sq);
  };

  // CONSUMER: poll private stamp, read r.
  auto getR = [&](int s) {
    const uint32_t sq = (uint32_t)(s + 1);
    if (tid == 0) {
      while (ATL32(rst + bid * 4) < sq) __builtin_amdgcn_s_sleep(1);
    }
    __syncthreads();
    asm volatile("" ::: "memory");
    if (tid < 64) rS[tid] = ATL32(ws + WS_RBUF + tid);
    __syncthreads();
  };

  // quad partial for this block's Q-slice (bit-identical to R5) -> stamped QP
  auto quadPub = [&](int s) {
    const uint32_t sq = (uint32_t)(s + 1);
    if (tid < 256) {
      const int jl = tid >> 4, kc = tid & 15;
      const float* qr = Qs + jl * 64 + kc * 4;
      float t0 = qr[0] * rS[kc * 4];
      t0 = fmaf(qr[1], rS[kc * 4 + 1], t0);
      t0 = fmaf(qr[2], rS[kc * 4 + 2], t0);
      t0 = fmaf(qr[3], rS[kc * 4 + 3], t0);
      redA[tid] = t0 * rS[(bid & 3) * 16 + jl];
    }
    __syncthreads();
    for (int st = 128; st > 0; st >>= 1) {
      if (tid < st) redA[tid] += redA[tid + st];
      __syncthreads();
    }
    if (tid == 0) ATS64(qp64 + bid, packfs(redA[0], sq));
  };

  auto meanH = [&](int s) {
    const uint32_t sq = (uint32_t)(s + 1);
    if (tid < 64) {
      uint64_t* qb = qp64 + tid * 4;
      float q0 = poll64b(qb + 0, sq);
      float q1 = poll64b(qb + 1, sq);
      float q2 = poll64b(qb + 2, sq);
      float q3 = poll64b(qb + 3, sq);
      float qd = q0 + q1 + q2 + q3;
      float ar = 0.0f;
      const float* arow = As + tid * 64;
      for (int k2 = 0; k2 < 64; ++k2) ar = fmaf(arow[k2], rS[k2], ar);
      mnS[tid] = rS[tid] + 0.0099f * (ar + qd);
    }
    __syncthreads();
    asm volatile("" ::: "memory");
    if (tid < 32) {
      float hv = ws[WS_B + (s + 1) * 32 + tid];
      const float* wrow = Wm + tid * 64;
      for (int d = 0; d < 64; ++d) hv = fmaf(-wrow[d], mnS[d], hv);
      hC[tid] = hv;
    }
    __syncthreads();
  };

  // ---- init: X0 with k_init; z = b0 - W X0; gumbel uk[0]; publish stamp 1 ----
  genE8(keyL[258], keyL[259]);
  genG(keyL[128], keyL[129]);
  ringME(Wm);
  tailStore(1u);

  for (int s = 0; s < 64; ++s) {
    // shadow: PRNG + Mat*E for this step's transition (independent of h)
    genE8(keyL[2 * s], keyL[2 * s + 1]);
    genG(keyL[128 + 2 * (s + 1)], keyL[128 + 2 * (s + 1) + 1]);
    ringME(Ms);
    if (bid == 0) combA(s); else getR(s);
    quadPub(s);
    meanH(s);
    tailStore((uint32_t)(s + 2));
  }

  // ---- final: lml += logsumexp(lw_64); combiner reduces & writes ----
  if (bid == 0) {
    const uint32_t sq = 65u;
    float pml = 0.f, pzlv = 0.f;
    if (tid < 256) {
      uint64_t* bp = p4 + tid * 4;
      pml = poll64(bp + 1, sq);
      pzlv = poll64(bp + 3, sq);
      redB[tid] = pml;
    }
    __syncthreads();
    for (int st = 128; st > 0; st >>= 1) {
      if (tid < st) redB[tid] = fmaxf(redB[tid], redB[tid + st]);
      __syncthreads();
    }
    const float mlwg = redB[0];
    __syncthreads();
    if (tid < 256) redB[tid] = expf(pml - mlwg) * pzlv;
    __syncthreads();
    for (int st = 128; st > 0; st >>= 1) {
      if (tid < st) redB[tid] += redB[tid + st];
      __syncthreads();
    }
    if (tid == 0) dout[0] = sc[4] + mlwg + logf(redB[0]);
  }
}

extern "C" void kernel_launch(void* const* d_in, const int* in_sizes, int n_in,
                              void* d_out, int out_size, void* d_ws, size_t ws_size,
                              hipStream_t stream) {
  const float* obs = (const float*)d_in[0];
  const float* Am = (const float*)d_in[1];
  const float* Cm = (const float*)d_in[2];
  const float* Qt = (const float*)d_in[3];
  const float* Qc = (const float*)d_in[4];
  const float* Rc = (const float*)d_in[5];
  float* ws = (float*)d_ws;
  float* out = (float*)d_out;
  (void)in_sizes; (void)n_in; (void)out_size; (void)ws_size;

  kp_kernel<<<dim3(1), dim3(1024), 0, stream>>>(ws, obs, Cm, Qc, Rc);

  void* params[] = { (void*)&ws, (void*)&Am, (void*)&Qc, (void*)&Qt, (void*)&out };
  hipLaunchCooperativeKernel((const void*)kmain_kernel, dim3(256), dim3(512),
                             params, 0, stream);
}

// Round 7
// 1229.831 us; speedup vs baseline: 1.2018x; 1.2018x over previous
//
#include <hip/hip_runtime.h>
#include <cstdint>

#define NPART 32768
#define HALFN 16384

// ws float-offsets
#define WS_W     0        // [32][64]
#define WS_M     2048     // [32][64]
#define WS_B     4096     // [65][32]
#define WS_C0    6176
#define WS_KI    6178     // 2 uints
#define WS_NK    6180     // 128 uints
#define WS_UK    6308     // 130 uints -> 6438
#define WS_P4    6440     // per block 8 floats: [my, ml, zy, pad, zl_stamped(u64)] -> 8488
#define WS_PSE   8488     // float[256][64] -> 24872
#define WS_QP64  24872    // u64[256] seq-stamped -> 25384
#define WS_END   25384

#define ATS32(p, v) __hip_atomic_store((p), (v), __ATOMIC_RELAXED, __HIP_MEMORY_SCOPE_AGENT)
#define ATL32(p)    __hip_atomic_load((p), __ATOMIC_RELAXED, __HIP_MEMORY_SCOPE_AGENT)
#define ATS64(p, v) __hip_atomic_store((p), (v), __ATOMIC_RELAXED, __HIP_MEMORY_SCOPE_AGENT)
#define ATL64(p)    __hip_atomic_load((p), __ATOMIC_RELAXED, __HIP_MEMORY_SCOPE_AGENT)

struct HK { uint32_t a, b; };

// JAX threefry2x32 (20 rounds, 5 key injections)
__host__ __device__ inline HK tf2x32(uint32_t k0, uint32_t k1, uint32_t x0, uint32_t x1) {
  uint32_t kx = k0 ^ k1 ^ 0x1BD11BDAu;
#define TF_R(r) { x0 += x1; x1 = (x1 << (r)) | (x1 >> (32 - (r))); x1 ^= x0; }
  x0 += k0; x1 += k1;
  TF_R(13) TF_R(15) TF_R(26) TF_R(6)
  x0 += k1; x1 += kx + 1u;
  TF_R(17) TF_R(29) TF_R(16) TF_R(24)
  x0 += kx; x1 += k0 + 2u;
  TF_R(13) TF_R(15) TF_R(26) TF_R(6)
  x0 += k0; x1 += k1 + 3u;
  TF_R(17) TF_R(29) TF_R(16) TF_R(24)
  x0 += k1; x1 += kx + 4u;
  TF_R(13) TF_R(15) TF_R(26) TF_R(6)
  x0 += kx; x1 += k0 + 5u;
#undef TF_R
  HK r; r.a = x0; r.b = x1; return r;
}

// XLA ErfInv32 polynomial
__device__ inline float erfinv_f(float x) {
  float w = -log1pf(-x * x);
  float p;
  if (w < 5.0f) {
    w -= 2.5f;
    p = 2.81022636e-08f;
    p = fmaf(p, w, 3.43273939e-07f);
    p = fmaf(p, w, -3.5233877e-06f);
    p = fmaf(p, w, -4.39150654e-06f);
    p = fmaf(p, w, 0.00021858087f);
    p = fmaf(p, w, -0.00125372503f);
    p = fmaf(p, w, -0.00417768164f);
    p = fmaf(p, w, 0.246640727f);
    p = fmaf(p, w, 1.50140941f);
  } else {
    w = sqrtf(w) - 3.0f;
    p = -0.000200214257f;
    p = fmaf(p, w, 0.000100950558f);
    p = fmaf(p, w, 0.00134934322f);
    p = fmaf(p, w, -0.00367342844f);
    p = fmaf(p, w, 0.00573950773f);
    p = fmaf(p, w, -0.0076224613f);
    p = fmaf(p, w, 0.00943887047f);
    p = fmaf(p, w, 1.00167406f);
    p = fmaf(p, w, 2.83297682f);
  }
  return p * x;
}

__device__ inline float u01(uint32_t bits) {
  return __uint_as_float((bits >> 9) | 0x3f800000u) - 1.0f;
}

__device__ inline uint64_t packfs(float v, uint32_t sq) {
  return ((uint64_t)sq << 32) | (uint64_t)__float_as_uint(v);
}

// Precompute: chol(R), Linv, W = Linv C, M = W Qc, b[t] = Linv obs_t, C0, keys;
// zero all stamped exchange regions.
__global__ __launch_bounds__(1024) void kp_kernel(float* __restrict__ ws,
    const float* __restrict__ obs, const float* __restrict__ Cm,
    const float* __restrict__ Qc, const float* __restrict__ Rc) {
  __shared__ float Ls[32][32];
  __shared__ float Li[32][32];
  __shared__ float Wsh[32][64];
  const int tid = threadIdx.x;
  const int i = tid >> 5, j = tid & 31;
  uint32_t* wsu = (uint32_t*)ws;
  // zero exchange regions (stamps -> 0)
  for (int idx = WS_P4 + tid; idx < WS_END; idx += 1024) wsu[idx] = 0u;
  // keys (parallel over t)
  if (tid <= 64) {
    HK p0 = tf2x32(0u, 42u, 0u, 2u);
    HK p1 = tf2x32(0u, 42u, 1u, 3u);
    uint32_t ks0 = p0.b, ks1 = p1.b;
    HK f = tf2x32(ks0, ks1, 0u, (uint32_t)tid);
    HK q0 = tf2x32(f.a, f.b, 0u, 2u);
    HK q1 = tf2x32(f.a, f.b, 1u, 3u);
    wsu[WS_UK + 2 * tid] = q0.a; wsu[WS_UK + 2 * tid + 1] = q1.a;
    if (tid < 64) { wsu[WS_NK + 2 * tid] = q0.b; wsu[WS_NK + 2 * tid + 1] = q1.b; }
    if (tid == 0) { wsu[WS_KI] = p0.a; wsu[WS_KI + 1] = p1.a; }
  }
  // R = Rc Rc^T
  {
    float a = 0.0f;
    for (int k = 0; k < 32; ++k) a = fmaf(Rc[i * 32 + k], Rc[j * 32 + k], a);
    Ls[i][j] = a;
  }
  __syncthreads();
  for (int k = 0; k < 32; ++k) {
    if (tid == 0) Ls[k][k] = sqrtf(Ls[k][k]);
    __syncthreads();
    if (tid > k && tid < 32) Ls[tid][k] /= Ls[k][k];
    __syncthreads();
    if (i > k && j > k && j <= i) Ls[i][j] = fmaf(-Ls[i][k], Ls[j][k], Ls[i][j]);
    __syncthreads();
  }
  if (tid < 32) {
    for (int r = 0; r < 32; ++r) Li[r][tid] = 0.0f;
    Li[tid][tid] = 1.0f / Ls[tid][tid];
    for (int r = tid + 1; r < 32; ++r) {
      float s = 0.0f;
      for (int m = tid; m < r; ++m) s = fmaf(Ls[r][m], Li[m][tid], s);
      Li[r][tid] = -s / Ls[r][r];
    }
  }
  __syncthreads();
  if (tid == 0) {
    float ld = 0.0f;
    for (int k = 0; k < 32; ++k) ld += logf(Ls[k][k]);
    ws[WS_C0] = -0.5f * 32.0f * 1.8378770664093453f - ld;
  }
  for (int idx = tid; idx < 2048; idx += 1024) {
    int o = idx >> 6, d = idx & 63;
    float a = 0.0f;
    for (int k = 0; k < 32; ++k) a = fmaf(Li[o][k], Cm[k * 64 + d], a);
    Wsh[o][d] = a;
    ws[WS_W + idx] = a;
  }
  __syncthreads();
  for (int idx = tid; idx < 2048; idx += 1024) {
    int o = idx >> 6, d = idx & 63;
    float a = 0.0f;
    for (int k = 0; k < 64; ++k) a = fmaf(Wsh[o][k], Qc[k * 64 + d], a);
    ws[WS_M + idx] = a;
  }
  for (int idx = tid; idx < 2080; idx += 1024) {
    int t = idx >> 5, o = idx & 31;
    float a = 0.0f;
    for (int k = 0; k < 32; ++k) a = fmaf(Li[o][k], obs[t * 32 + k], a);
    ws[WS_B + idx] = a;
  }
}

// Persistent cooperative kernel: 256 blocks x 512 threads, all-combine
// dataflow (2 global exchanges/step), wave0 shfl-butterfly reductions
// (bit-identical bracketing to the old LDS trees), single-poll stamps.
__global__ __launch_bounds__(512, 2) void kmain_kernel(
    float* __restrict__ ws, const float* __restrict__ Am,
    const float* __restrict__ Qcg, const float* __restrict__ Qt,
    float* __restrict__ dout) {
  __shared__ __align__(16) float Ms[2048];
  __shared__ __align__(16) float Wm[2048];
  __shared__ __align__(16) float As[4096];
  __shared__ __align__(16) float Qcs[4096];
  __shared__ __align__(16) float Qs[1024];
  __shared__ float hC[32];
  __shared__ float rS[64], uS[64], mnS[64];
  __shared__ float ebL[256];
  __shared__ float redA[256], redB[256], redC[256], redD[256];
  __shared__ float SEw[8][64];
  __shared__ float wred[8][4];
  __shared__ float sc[8];
  __shared__ uint32_t keyL[260];  // [0..127] nk, [128..257] uk, [258..259] ki

  const int tid = threadIdx.x;
  const int bid = blockIdx.x;
  uint32_t* wsu = (uint32_t*)ws;
  uint64_t* qp64 = (uint64_t*)(ws + WS_QP64);

  // prologue loads (read-only data; plain cached loads)
  for (int i = tid; i < 2048; i += 512) { Ms[i] = ws[WS_M + i]; Wm[i] = ws[WS_W + i]; }
  for (int i = tid; i < 4096; i += 512) { As[i] = Am[i]; Qcs[i] = Qcg[i]; }
  {
    const int i0 = (bid >> 2) * 4096 + (bid & 3) * 1024;
    for (int i = tid; i < 1024; i += 512) Qs[i] = Qt[i0 + i];
  }
  for (int i = tid; i < 128; i += 512) keyL[i] = wsu[WS_NK + i];
  for (int i = tid; i < 130; i += 512) keyL[128 + i] = wsu[WS_UK + i];
  if (tid == 0) { keyL[258] = wsu[WS_KI]; keyL[259] = wsu[WS_KI + 1]; sc[4] = 0.0f; }
  if (tid < 32) hC[tid] = ws[WS_B + tid];
  const float C0 = ws[WS_C0];
  __syncthreads();

  const int pr = tid >> 3;          // pair within block
  const int l8 = tid & 7;
  const int p = bid * 64 + pr;      // global pair (= lo particle)
  const int d0 = l8 * 8;
  const int wv = tid >> 6, ln = tid & 63;

  float Elo[8], Ehi[8], gl, gh;
  float aL[4], aH[4];

  auto poll64 = [&](uint64_t* pp, uint32_t sq) -> float {
    uint64_t q;
    for (;;) {
      q = ATL64(pp);
      if ((uint32_t)(q >> 32) >= sq) break;
      __builtin_amdgcn_s_sleep(1);
    }
    return __uint_as_float((uint32_t)q);
  };

  auto genE8 = [&](uint32_t k0, uint32_t k1) {
    const uint32_t fb = (uint32_t)(p * 64 + d0);
#pragma unroll
    for (int j = 0; j < 8; ++j) {
      HK o = tf2x32(k0, k1, fb + (uint32_t)j, fb + (uint32_t)j + 1048576u);
      float fl = u01(o.a), fh = u01(o.b);
      float ul = fmaxf(-0.99999994f, fmaf(fl, 2.0f, -0.99999994f));
      float uh = fmaxf(-0.99999994f, fmaf(fh, 2.0f, -0.99999994f));
      Elo[j] = 1.41421354f * erfinv_f(ul);
      Ehi[j] = 1.41421354f * erfinv_f(uh);
    }
  };
  auto genG = [&](uint32_t k0, uint32_t k1) {
    HK og = tf2x32(k0, k1, (uint32_t)p, (uint32_t)(p + 16384));
    gl = -logf(-logf(u01(og.a) + 1e-10f) + 1e-10f);
    gh = -logf(-logf(u01(og.b) + 1e-10f) + 1e-10f);
  };

  auto ringME = [&](const float* matL) {
#pragma unroll
    for (int q = 0; q < 4; ++q) { aL[q] = 0.f; aH[q] = 0.f; }
#pragma unroll
    for (int k = 0; k < 8; ++k) {
      if (k) {
#pragma unroll
        for (int q = 0; q < 4; ++q) {
          aL[q] = __shfl(aL[q], (l8 + 1) & 7, 8);
          aH[q] = __shfl(aH[q], (l8 + 1) & 7, 8);
        }
      }
      const int ow = ((l8 + k) & 7) * 4;
#pragma unroll
      for (int q = 0; q < 4; ++q) {
        const float* mr = matL + (ow + q) * 64 + d0;
        float4 m0 = *(const float4*)mr;
        float4 m1 = *(const float4*)(mr + 4);
        float t0 = aL[q];
        t0 = fmaf(m0.x, Elo[0], t0); t0 = fmaf(m0.y, Elo[1], t0);
        t0 = fmaf(m0.z, Elo[2], t0); t0 = fmaf(m0.w, Elo[3], t0);
        t0 = fmaf(m1.x, Elo[4], t0); t0 = fmaf(m1.y, Elo[5], t0);
        t0 = fmaf(m1.z, Elo[6], t0); t0 = fmaf(m1.w, Elo[7], t0);
        aL[q] = t0;
        float t1 = aH[q];
        t1 = fmaf(m0.x, Ehi[0], t1); t1 = fmaf(m0.y, Ehi[1], t1);
        t1 = fmaf(m0.z, Ehi[2], t1); t1 = fmaf(m0.w, Ehi[3], t1);
        t1 = fmaf(m1.x, Ehi[4], t1); t1 = fmaf(m1.y, Ehi[5], t1);
        t1 = fmaf(m1.z, Ehi[6], t1); t1 = fmaf(m1.w, Ehi[7], t1);
        aH[q] = t1;
      }
    }
  };

  // z = hC - Mat*E; lw, y, block softmax partials + weighted-E sums;
  // publish PSE + 3 plain P4 floats, vmcnt drain, ONE stamped u64.
  auto tailStore = [&](uint32_t sq) {
    const int ob = ((l8 + 7) & 7) * 4;
    float s2l = 0.f, s2h = 0.f;
#pragma unroll
    for (int q = 0; q < 4; ++q) {
      float zl = hC[ob + q] - aL[q], zh = hC[ob + q] - aH[q];
      s2l = fmaf(zl, zl, s2l); s2h = fmaf(zh, zh, s2h);
    }
#pragma unroll
    for (int m = 1; m < 8; m <<= 1) { s2l += __shfl_xor(s2l, m, 8); s2h += __shfl_xor(s2h, m, 8); }
    const float lwL = C0 - 0.5f * s2l, lwH = C0 - 0.5f * s2h;
    const float yl = (lwL + gl) * 2.0f, yh = (lwH + gh) * 2.0f;
    float mv = fmaxf(yl, yh), ml = fmaxf(lwL, lwH);
#pragma unroll
    for (int m = 1; m < 64; m <<= 1) {
      mv = fmaxf(mv, __shfl_xor(mv, m, 64));
      ml = fmaxf(ml, __shfl_xor(ml, m, 64));
    }
    if (ln == 0) { wred[wv][0] = mv; wred[wv][1] = ml; }
    __syncthreads();
    if (tid == 0) {
      float a = wred[0][0], b = wred[0][1];
      for (int q = 1; q < 8; ++q) { a = fmaxf(a, wred[q][0]); b = fmaxf(b, wred[q][1]); }
      sc[0] = a; sc[1] = b;
    }
    __syncthreads();
    const float myb = sc[0], mlb = sc[1];
    const float wLo = expf(yl - myb), wHi = expf(yh - myb);
    float vzy = (l8 == 0) ? (wLo + wHi) : 0.0f;
    float vzl = (l8 == 0) ? (expf(lwL - mlb) + expf(lwH - mlb)) : 0.0f;
#pragma unroll
    for (int m = 1; m < 64; m <<= 1) { vzy += __shfl_xor(vzy, m, 64); vzl += __shfl_xor(vzl, m, 64); }
    if (ln == 0) { wred[wv][2] = vzy; wred[wv][3] = vzl; }
    float v[8];
#pragma unroll
    for (int j = 0; j < 8; ++j) v[j] = fmaf(wHi, Ehi[j], wLo * Elo[j]);
#pragma unroll
    for (int m = 8; m < 64; m <<= 1) {
#pragma unroll
      for (int j = 0; j < 8; ++j) v[j] += __shfl_xor(v[j], m, 64);
    }
    if (ln < 8) {
#pragma unroll
      for (int j = 0; j < 8; ++j) SEw[wv][ln * 8 + j] = v[j];
    }
    __syncthreads();
    float zl2 = 0.0f;
    if (tid < 64) {
      float ssum = SEw[0][tid];
      for (int q = 1; q < 8; ++q) ssum += SEw[q][tid];
      ATS32(ws + WS_PSE + (bid << 6) + tid, ssum);
    }
    if (tid == 0) {
      float zy = wred[0][2];
      zl2 = wred[0][3];
      for (int q = 1; q < 8; ++q) { zy += wred[q][2]; zl2 += wred[q][3]; }
      float* pb = ws + WS_P4 + (bid << 3);
      ATS32(pb + 0, sc[0]);
      ATS32(pb + 1, sc[1]);
      ATS32(pb + 2, zy);
    }
    if (tid < 64) asm volatile("s_waitcnt vmcnt(0)" ::: "memory");
    if (tid == 0)
      ATS64((uint64_t*)(ws + WS_P4 + (bid << 3) + 4), packfs(zl2, sq));
  };

  // all-combine: single-poll stamps, wave0 butterfly trees (bit-identical
  // bracketing to pairwise LDS tree at lane 0), PSE prefetch overlap.
  auto combine = [&](int s) {
    const uint32_t sq = (uint32_t)(s + 1);
    if (tid < 256) {
      float* pb = ws + WS_P4 + (tid << 3);
      float zl = poll64((uint64_t*)(pb + 4), sq);
      asm volatile("" ::: "memory");
      redA[tid] = ATL32(pb + 0);
      redB[tid] = ATL32(pb + 1);
      redC[tid] = ATL32(pb + 2);
      redD[tid] = zl;
    }
    __syncthreads();
    // PSE prefetch (stamps all seen -> data valid at LLC)
    float pse[32];
    const int d = tid & 63, c = tid >> 6;
#pragma unroll
    for (int b8 = 0; b8 < 32; ++b8)
      pse[b8] = ATL32(ws + WS_PSE + (((c << 5) + b8) << 6) + d);
    if (tid < 64) {
      const int l = tid;
      float a0 = redA[l], a1 = redA[l + 64], a2 = redA[l + 128], a3 = redA[l + 192];
      float b0 = redB[l], b1 = redB[l + 64], b2 = redB[l + 128], b3 = redB[l + 192];
      float myg = fmaxf(fmaxf(a0, a2), fmaxf(a1, a3));
      float mlg = fmaxf(fmaxf(b0, b2), fmaxf(b1, b3));
#pragma unroll
      for (int m = 32; m >= 1; m >>= 1) {
        myg = fmaxf(myg, __shfl_xor(myg, m, 64));
        mlg = fmaxf(mlg, __shfl_xor(mlg, m, 64));
      }
      myg = __shfl(myg, 0, 64); mlg = __shfl(mlg, 0, 64);
      float zy0 = redC[l], zy1 = redC[l + 64], zy2 = redC[l + 128], zy3 = redC[l + 192];
      float zl0 = redD[l], zl1 = redD[l + 64], zl2 = redD[l + 128], zl3 = redD[l + 192];
      float e0 = expf(a0 - myg), e1 = expf(a1 - myg), e2 = expf(a2 - myg), e3 = expf(a3 - myg);
      ebL[l] = e0; ebL[l + 64] = e1; ebL[l + 128] = e2; ebL[l + 192] = e3;
      float zyS = (e0 * zy0 + e2 * zy2) + (e1 * zy1 + e3 * zy3);
      float f0 = expf(b0 - mlg) * zl0, f1 = expf(b1 - mlg) * zl1;
      float f2 = expf(b2 - mlg) * zl2, f3 = expf(b3 - mlg) * zl3;
      float zlS = (f0 + f2) + (f1 + f3);
#pragma unroll
      for (int m = 32; m >= 1; m >>= 1) {
        zyS += __shfl_xor(zyS, m, 64);
        zlS += __shfl_xor(zlS, m, 64);
      }
      if (l == 0) {
        sc[2] = zyS;
        if (s > 0) sc[4] += mlg + logf(zlS);
      }
    }
    __syncthreads();
    const float Zy = sc[2];
    {
      float pp = 0.0f;
#pragma unroll
      for (int b8 = 0; b8 < 32; ++b8)
        pp = fmaf(ebL[(c << 5) + b8], pse[b8], pp);
      SEw[c][d] = pp;
    }
    __syncthreads();
    if (tid < 64) {
      float sg = SEw[0][tid];
      for (int cc = 1; cc < 8; ++cc) sg += SEw[cc][tid];
      uS[tid] = sg / Zy;
    }
    __syncthreads();
    if (tid < 64) {
      float r;
      if (s == 0) r = uS[tid];
      else {
        r = mnS[tid];
        const float* qr = Qcs + tid * 64;
        for (int k2 = 0; k2 < 64; ++k2) r = fmaf(uS[k2], qr[k2], r);
      }
      rS[tid] = r;
    }
    __syncthreads();
  };

  // quad partial for this block's Q-slice -> stamped QP (wave0 butterfly)
  auto quadPub = [&](int s) {
    const uint32_t sq = (uint32_t)(s + 1);
    if (tid < 256) {
      const int jl = tid >> 4, kc = tid & 15;
      const float* qr = Qs + jl * 64 + kc * 4;
      float t0 = qr[0] * rS[kc * 4];
      t0 = fmaf(qr[1], rS[kc * 4 + 1], t0);
      t0 = fmaf(qr[2], rS[kc * 4 + 2], t0);
      t0 = fmaf(qr[3], rS[kc * 4 + 3], t0);
      redA[tid] = t0 * rS[(bid & 3) * 16 + jl];
    }
    __syncthreads();
    if (tid < 64) {
      float q0 = redA[tid], q1 = redA[tid + 64], q2 = redA[tid + 128], q3 = redA[tid + 192];
      float qs = (q0 + q2) + (q1 + q3);
#pragma unroll
      for (int m = 32; m >= 1; m >>= 1) qs += __shfl_xor(qs, m, 64);
      if (tid == 0) ATS64(qp64 + bid, packfs(qs, sq));
    }
  };

  auto meanH = [&](int s) {
    const uint32_t sq = (uint32_t)(s + 1);
    if (tid < 64) {
      float ar = 0.0f;
      const float* arow = As + tid * 64;
      for (int k2 = 0; k2 < 64; ++k2) ar = fmaf(arow[k2], rS[k2], ar);
      uint64_t* qb = qp64 + (tid << 2);
      uint64_t u0, u1, u2, u3;
      for (;;) {
        u0 = ATL64(qb + 0); u1 = ATL64(qb + 1);
        u2 = ATL64(qb + 2); u3 = ATL64(qb + 3);
        bool ok = ((uint32_t)(u0 >> 32) >= sq) && ((uint32_t)(u1 >> 32) >= sq) &&
                  ((uint32_t)(u2 >> 32) >= sq) && ((uint32_t)(u3 >> 32) >= sq);
        if (__all(ok)) break;
        __builtin_amdgcn_s_sleep(1);
      }
      float qd = __uint_as_float((uint32_t)u0) + __uint_as_float((uint32_t)u1) +
                 __uint_as_float((uint32_t)u2) + __uint_as_float((uint32_t)u3);
      mnS[tid] = rS[tid] + 0.0099f * (ar + qd);
    }
    __syncthreads();
    asm volatile("" ::: "memory");
    if (tid < 32) {
      float hv = ws[WS_B + (s + 1) * 32 + tid];
      const float* wrow = Wm + tid * 64;
      for (int d2 = 0; d2 < 64; ++d2) hv = fmaf(-wrow[d2], mnS[d2], hv);
      hC[tid] = hv;
    }
    __syncthreads();
  };

  // ---- init: X0 with k_init; z = b0 - W X0; gumbel uk[0]; publish stamp 1 ----
  genE8(keyL[258], keyL[259]);
  genG(keyL[128], keyL[129]);
  ringME(Wm);
  tailStore(1u);

  for (int s = 0; s < 64; ++s) {
    // shadow: PRNG + Mat*E for this step's transition (independent of h)
    genE8(keyL[2 * s], keyL[2 * s + 1]);
    genG(keyL[128 + 2 * (s + 1)], keyL[128 + 2 * (s + 1) + 1]);
    ringME(Ms);
    combine(s);
    quadPub(s);
    meanH(s);
    tailStore((uint32_t)(s + 2));
  }

  // ---- final: lml += logsumexp(lw_64); block0 reduces & writes ----
  if (bid == 0) {
    const uint32_t sq = 65u;
    float pml = 0.f, pzlv = 0.f;
    if (tid < 256) {
      float* pb = ws + WS_P4 + (tid << 3);
      pzlv = poll64((uint64_t*)(pb + 4), sq);
      asm volatile("" ::: "memory");
      pml = ATL32(pb + 1);
      redB[tid] = pml;
    }
    __syncthreads();
    for (int st = 128; st > 0; st >>= 1) {
      if (tid < st) redB[tid] = fmaxf(redB[tid], redB[tid + st]);
      __syncthreads();
    }
    const float mlwg = redB[0];
    __syncthreads();
    if (tid < 256) redB[tid] = expf(pml - mlwg) * pzlv;
    __syncthreads();
    for (int st = 128; st > 0; st >>= 1) {
      if (tid < st) redB[tid] += redB[tid + st];
      __syncthreads();
    }
    if (tid == 0) dout[0] = sc[4] + mlwg + logf(redB[0]);
  }
}

extern "C" void kernel_launch(void* const* d_in, const int* in_sizes, int n_in,
                              void* d_out, int out_size, void* d_ws, size_t ws_size,
                              hipStream_t stream) {
  const float* obs = (const float*)d_in[0];
  const float* Am = (const float*)d_in[1];
  const float* Cm = (const float*)d_in[2];
  const float* Qt = (const float*)d_in[3];
  const float* Qc = (const float*)d_in[4];
  const float* Rc = (const float*)d_in[5];
  float* ws = (float*)d_ws;
  float* out = (float*)d_out;
  (void)in_sizes; (void)n_in; (void)out_size; (void)ws_size;

  kp_kernel<<<dim3(1), dim3(1024), 0, stream>>>(ws, obs, Cm, Qc, Rc);

  void* params[] = { (void*)&ws, (void*)&Am, (void*)&Qc, (void*)&Qt, (void*)&out };
  hipLaunchCooperativeKernel((const void*)kmain_kernel, dim3(256), dim3(512),
                             params, 0, stream);
}